// Round 1
// baseline (364.252 us; speedup 1.0000x reference)
//
#include <hip/hip_runtime.h>

// ---------- helpers ----------
typedef __attribute__((ext_vector_type(8))) __bf16 bf16x8;
typedef __attribute__((ext_vector_type(4))) float f32x4;

__device__ inline unsigned short f2bf(float f) {
    union { float f; unsigned int i; } v; v.f = f;
    unsigned int i = v.i;
    unsigned int r = i + 0x7FFFu + ((i >> 16) & 1u);   // RNE
    return (unsigned short)(r >> 16);
}
__device__ inline float bf2f(unsigned short u) {
    union { unsigned int i; float f; } v; v.i = ((unsigned int)u) << 16; return v.f;
}

__device__ inline void gload_lds16(const void* g, void* l) {
    __builtin_amdgcn_global_load_lds(
        (const __attribute__((address_space(1))) unsigned int*)g,
        (__attribute__((address_space(3))) unsigned int*)l, 16, 0, 0);
}

// ---------- kernel 1: cast x (fp32 -> bf16) ----------
__global__ __launch_bounds__(256) void cast_x(const float* __restrict__ x,
                                              unsigned short* __restrict__ xb, int n4) {
    int idx = blockIdx.x * blockDim.x + threadIdx.x;
    int stride = gridDim.x * blockDim.x;
    for (int i = idx; i < n4; i += stride) {
        float4 v = ((const float4*)x)[i];
        ushort4 o;
        o.x = f2bf(v.x); o.y = f2bf(v.y); o.z = f2bf(v.z); o.w = f2bf(v.w);
        ((ushort4*)xb)[i] = o;
    }
}

// ---------- kernel 2: cast W into Wcat rows 0..1023 ----------
__global__ __launch_bounds__(256) void cast_w(const float* __restrict__ W,
                                              unsigned short* __restrict__ wcat) {
    int i = blockIdx.x * 256 + threadIdx.x;      // 1024 blocks -> 262144 threads, 4 elems each
    float4 v = ((const float4*)W)[i];
    ushort4 o;
    o.x = f2bf(v.x); o.y = f2bf(v.y); o.z = f2bf(v.z); o.w = f2bf(v.w);
    ((ushort4*)wcat)[i] = o;
}

// ---------- kernel 3: build M^T into Wcat rows 1024..2047 ----------
// M[d][D] = sum_e p_e sum_r A[e,d,r] * B[e,r,D];  Wcat[1024+D][d] = M[d][D]
__global__ __launch_bounds__(256) void build_m(const float* __restrict__ A,
                                               const float* __restrict__ Bm,
                                               const float* __restrict__ scores,
                                               unsigned short* __restrict__ wcat) {
    int D = blockIdx.x;      // 1024
    int tx = threadIdx.x;    // 256, each thread handles 4 d values
    float acc[4] = {0.f, 0.f, 0.f, 0.f};
    for (int e = 0; e < 16; ++e) {
        float pe = scores[e];
        float bb[16];
        #pragma unroll
        for (int r = 0; r < 16; ++r) bb[r] = pe * Bm[(size_t)((e << 4) + r) * 1024 + D];
        #pragma unroll
        for (int j = 0; j < 4; ++j) {
            int d = tx + j * 256;
            const float4* ap = (const float4*)(A + (((size_t)e * 1024 + d) << 4));
            float4 a0 = ap[0], a1 = ap[1], a2 = ap[2], a3 = ap[3];
            acc[j] += a0.x*bb[0]  + a0.y*bb[1]  + a0.z*bb[2]  + a0.w*bb[3]
                    + a1.x*bb[4]  + a1.y*bb[5]  + a1.z*bb[6]  + a1.w*bb[7]
                    + a2.x*bb[8]  + a2.y*bb[9]  + a2.z*bb[10] + a2.w*bb[11]
                    + a3.x*bb[12] + a3.y*bb[13] + a3.z*bb[14] + a3.w*bb[15];
        }
    }
    size_t rowbase = (size_t)(1024 + D) * 1024;
    #pragma unroll
    for (int j = 0; j < 4; ++j) wcat[rowbase + tx + j * 256] = f2bf(acc[j]);
}

// ---------- kernel 4: GEMM  out2[t][n] = sum_k xb[t][k] * wcat[n][k] ----------
// 128x128 tile, BK=32, 4 waves (2x2), 16x16x32 bf16 MFMA, global_load_lds width=16.
// n < 1024  -> z half: + bias, fp32 -> zout (d_out)
// n >= 1024 -> m half: bf16 -> mbuf (ws)
__global__ __launch_bounds__(256) void gemm_zm(const unsigned short* __restrict__ xb,
                                               const unsigned short* __restrict__ wcat,
                                               const float* __restrict__ bias,
                                               float* __restrict__ zout,
                                               unsigned short* __restrict__ mbuf) {
    const int K = 1024;
    __shared__ unsigned short As[128 * 32];   // [row][k], k contiguous (32 bf16 = 64B rows)
    __shared__ unsigned short Bs[128 * 32];

    const int brow = blockIdx.y * 128;        // 256 tiles
    const int bcol = blockIdx.x * 128;        // 16 tiles
    const int t = threadIdx.x;
    const int l = t & 63;
    const int w = t >> 6;
    const int wr = w >> 1, wc = w & 1;        // 2x2 wave grid, each wave 64x64

    f32x4 acc[4][4] = {};

    const int lrow = l & 15;
    const int lk = (l >> 4) * 8;

    for (int k0 = 0; k0 < K; k0 += 32) {
        #pragma unroll
        for (int i = 0; i < 2; ++i) {
            int c = i * 256 + t;              // 16B chunk index, 4 chunks per row
            int r = c >> 2;
            int kk = (c & 3) * 8;
            gload_lds16(xb   + (size_t)(brow + r) * K + k0 + kk, &As[c * 8]);
            gload_lds16(wcat + (size_t)(bcol + r) * K + k0 + kk, &Bs[c * 8]);
        }
        __syncthreads();

        bf16x8 a[4], b[4];
        #pragma unroll
        for (int m = 0; m < 4; ++m)
            a[m] = *(const bf16x8*)&As[(wr * 64 + m * 16 + lrow) * 32 + lk];
        #pragma unroll
        for (int n = 0; n < 4; ++n)
            b[n] = *(const bf16x8*)&Bs[(wc * 64 + n * 16 + lrow) * 32 + lk];

        #pragma unroll
        for (int m = 0; m < 4; ++m)
            #pragma unroll
            for (int n = 0; n < 4; ++n)
                acc[m][n] = __builtin_amdgcn_mfma_f32_16x16x32_bf16(a[m], b[n], acc[m][n], 0, 0, 0);
        __syncthreads();
    }

    // epilogue: C/D layout col = l&15, row = (l>>4)*4 + j   [verified m89]
    const bool is_z = (bcol < 1024);
    #pragma unroll
    for (int m = 0; m < 4; ++m) {
        int row = brow + wr * 64 + m * 16 + (l >> 4) * 4;
        #pragma unroll
        for (int n = 0; n < 4; ++n) {
            int col = bcol + wc * 64 + n * 16 + (l & 15);
            f32x4 v = acc[m][n];
            if (is_z) {
                float bb = bias[col];
                #pragma unroll
                for (int j = 0; j < 4; ++j)
                    zout[(size_t)(row + j) * 1024 + col] = v[j] + bb;
            } else {
                int mc = col - 1024;
                #pragma unroll
                for (int j = 0; j < 4; ++j)
                    mbuf[(size_t)(row + j) * 1024 + mc] = f2bf(v[j]);
            }
        }
    }
}

// ---------- kernel 5: norm-clamp epilogue, rewrites d_out in place ----------
__global__ __launch_bounds__(256) void epilogue(float* __restrict__ out,
                                                const unsigned short* __restrict__ mbuf,
                                                const int* __restrict__ lidx) {
    int row = blockIdx.x;            // 32768
    int tx = threadIdx.x;            // 256, 4 cols each
    size_t base = (size_t)row * 1024 + tx * 4;

    float4 z = *(const float4*)&out[base];
    ushort4 mv = *(const ushort4*)&mbuf[base];
    float m0 = bf2f(mv.x), m1 = bf2f(mv.y), m2 = bf2f(mv.z), m3 = bf2f(mv.w);

    float sz = z.x * z.x + z.y * z.y + z.z * z.z + z.w * z.w;
    float sm = m0 * m0 + m1 * m1 + m2 * m2 + m3 * m3;

    #pragma unroll
    for (int off = 32; off > 0; off >>= 1) {
        sz += __shfl_xor(sz, off);
        sm += __shfl_xor(sm, off);
    }
    __shared__ float red[8];
    int wv = tx >> 6;
    if ((tx & 63) == 0) { red[wv * 2] = sz; red[wv * 2 + 1] = sm; }
    __syncthreads();
    sz = red[0] + red[2] + red[4] + red[6];
    sm = red[1] + red[3] + red[5] + red[7];

    float gamma = fminf(0.5f * sqrtf(sz) / (sqrtf(sm) + 1e-6f), 1.0f);
    if (lidx[0] < 0) gamma = 0.f;    // L_START = 0: adapters off only if layer_idx < 0

    float4 o;
    o.x = z.x + gamma * m0; o.y = z.y + gamma * m1;
    o.z = z.z + gamma * m2; o.w = z.w + gamma * m3;
    *(float4*)&out[base] = o;
}

// ---------- launcher ----------
extern "C" void kernel_launch(void* const* d_in, const int* in_sizes, int n_in,
                              void* d_out, int out_size, void* d_ws, size_t ws_size,
                              hipStream_t stream) {
    const float* x  = (const float*)d_in[0];
    const float* W  = (const float*)d_in[1];
    const float* b  = (const float*)d_in[2];
    const float* A  = (const float*)d_in[3];
    const float* Bm = (const float*)d_in[4];
    const float* sc = (const float*)d_in[5];
    const int* lidx = (const int*)d_in[6];
    float* out = (float*)d_out;

    // workspace layout (bytes): xb 64MB | wcat 4MB | mbuf 64MB  (132MB total)
    unsigned short* xb   = (unsigned short*)d_ws;
    unsigned short* wcat = (unsigned short*)((char*)d_ws + 67108864);
    unsigned short* mbuf = (unsigned short*)((char*)d_ws + 71303168);

    cast_x<<<2048, 256, 0, stream>>>(x, xb, 33554432 / 4);
    cast_w<<<1024, 256, 0, stream>>>(W, wcat);
    build_m<<<1024, 256, 0, stream>>>(A, Bm, sc, wcat);
    gemm_zm<<<dim3(16, 256), 256, 0, stream>>>(xb, wcat, b, out, mbuf);
    epilogue<<<32768, 256, 0, stream>>>(out, mbuf, lidx);
}